// Round 8
// baseline (697.121 us; speedup 1.0000x reference)
//
#include <hip/hip_runtime.h>
#include <hip/hip_bf16.h>
#include <math.h>

#define NTAG 96
#define NB   128
#define SLEN 2048
#define CPERB (SLEN * NTAG)     // floats per batch row of em
#define NCH  8                  // chunks per sequence
#define CHUNK 256               // steps per chunk

typedef __attribute__((ext_vector_type(8)))  short bf16x8;
typedef __attribute__((ext_vector_type(4)))  float f32x4;
typedef __attribute__((ext_vector_type(16))) float f32x16;
union U8 { unsigned int u[4]; bf16x8 v; };

__device__ __forceinline__ unsigned int pk2bf(float lo, float hi) {
    union { __hip_bfloat16 h; unsigned short u; } a, b;
    a.h = __float2bfloat16(lo);
    b.h = __float2bfloat16(hi);
    return (unsigned int)a.u | ((unsigned int)b.u << 16);
}

__device__ __forceinline__ float waveSum(float v) {
    #pragma unroll
    for (int o = 32; o > 0; o >>= 1) v += __shfl_xor(v, o);
    return v;
}

// ---------------------------------------------------------------------------
// exp_pass: eexp[i] = exp(em[i]) elementwise, layout preserved. Memory-bound.
// ---------------------------------------------------------------------------
__global__ __launch_bounds__(256) void exp_pass(
    const float* __restrict__ x, float* __restrict__ y)
{
    size_t i = (size_t)blockIdx.x * 256 + threadIdx.x;   // one f32x4 each
    f32x4 v = ((const f32x4*)x)[i];
    f32x4 o;
    o[0] = __expf(v[0]); o[1] = __expf(v[1]);
    o[2] = __expf(v[2]); o[3] = __expf(v[3]);
    ((f32x4*)y)[i] = o;
}

// ---------------------------------------------------------------------------
// Phase 1 (32-wide): per (batch, chunk, strip32) wave computes a 96x32
// column strip of  M <- diag(e_t) * Texp^T * M,  M init = Identity, using
// full-rate mfma_f32_32x32x16_bf16.
//   C layout (verified m74/m101): col=lane&31, row=(reg&3)+8(reg>>2)+4h
//   B layout: col=lane&31, k=(lane>>5)*8+e
// Relayout C->B: 24 pk2bf + 12 shfl_xor(32) + selects (no LDS, no barriers).
// IEXP=1: srcE raw em (exp inline). IEXP=0: srcE = eexp.
// ---------------------------------------------------------------------------
template <int IEXP>
__global__ __launch_bounds__(64, 2) void crf_chunk32(
    const float* __restrict__ srcE, const float* __restrict__ mask,
    const float* __restrict__ trans,
    float* __restrict__ P, float* __restrict__ Pls)
{
    const int tid = threadIdx.x;
    const int c = tid & 31;          // strip column
    const int h = tid >> 5;          // half (row offset +4h, k offset +8h)

    // XCD-bijective decode: 3 strips of one (b,c) adjacent on one XCD.
    const int k   = blockIdx.x;          // 0..3071
    const int xcd = k & 7;
    const int seq = k >> 3;              // 0..383
    const int w2  = seq % 3;             // strip: columns 32*w2..32*w2+31
    const int bcg = seq / 3;             // 0..127
    const int bc  = bcg * 8 + xcd;       // b*NCH + chunk
    const int cch = bc & (NCH - 1);
    const int b   = bc >> 3;
    const int t0  = 1 + cch * CHUNK;
    const int t1  = min(SLEN, t0 + CHUNK);

    // global max of transitions (uniform scale)
    float tm = -1e30f;
    for (int q = tid; q < NTAG * NTAG; q += 64) tm = fmaxf(tm, trans[q]);
    #pragma unroll
    for (int o = 32; o > 0; o >>= 1) tm = fmaxf(tm, __shfl_xor(tm, o));
    const float tmax = tm;

    // A frags: Af[jt][kt] elem e = exp(trans[16kt+8h+e][32jt+c]-tmax)
    U8 Af[3][6];
    #pragma unroll
    for (int jt = 0; jt < 3; ++jt) {
        #pragma unroll
        for (int kt = 0; kt < 6; ++kt) {
            #pragma unroll
            for (int d = 0; d < 4; ++d) {
                int i0 = 16 * kt + 8 * h + 2 * d;
                Af[jt][kt].u[d] = pk2bf(
                    __expf(trans[i0 * NTAG + 32 * jt + c] - tmax),
                    __expf(trans[(i0 + 1) * NTAG + 32 * jt + c] - tmax));
            }
        }
    }

    // state S[rt][r] = M[32rt + (r&3)+8(r>>2)+4h][32w2 + c]; init identity.
    float S[3][16];
    #pragma unroll
    for (int rt = 0; rt < 3; ++rt) {
        #pragma unroll
        for (int r = 0; r < 16; ++r)
            S[rt][r] = (32 * rt + (r & 3) + 8 * (r >> 2) + 4 * h == 32 * w2 + c)
                       ? 1.0f : 0.0f;
    }
    float ls = 0.0f;

#define RENORM() do { \
    float mx_ = S[0][0]; \
    _Pragma("unroll") \
    for (int rt_ = 0; rt_ < 3; ++rt_) { \
        _Pragma("unroll") \
        for (int r_ = 0; r_ < 16; ++r_) mx_ = fmaxf(mx_, S[rt_][r_]); \
    } \
    mx_ = fmaxf(mx_, __shfl_xor(mx_, 32)); \
    mx_ = fmaxf(mx_, 1e-30f); \
    float inv_ = 1.0f / mx_; \
    ls += __logf(mx_); \
    _Pragma("unroll") \
    for (int rt_ = 0; rt_ < 3; ++rt_) { \
        _Pragma("unroll") \
        for (int r_ = 0; r_ < 16; ++r_) S[rt_][r_] *= inv_; \
    } \
} while (0)

    // Relayout: pk[rt][p] = bf16 pair of rows (2(p&1)+8(p>>1)+4h, +1), col c.
    // Bu[kt].u[d] = pk[kt>>1][4(kt&1)+2h_dst+(d&1)] from half h_src=(d>>1).
    // Partner (xor 32) pre-selects what this half needs (Y trick).
    U8 Bu[6];
#define MAKEB() do { \
    unsigned int pk_[3][8]; \
    _Pragma("unroll") \
    for (int rt_ = 0; rt_ < 3; ++rt_) { \
        _Pragma("unroll") \
        for (int p_ = 0; p_ < 8; ++p_) \
            pk_[rt_][p_] = pk2bf(S[rt_][2 * p_], S[rt_][2 * p_ + 1]); \
    } \
    _Pragma("unroll") \
    for (int kt_ = 0; kt_ < 6; ++kt_) { \
        const int rt_ = kt_ >> 1, q_ = 4 * (kt_ & 1); \
        unsigned int Y0_ = h ? pk_[rt_][q_]     : pk_[rt_][q_ + 2]; \
        unsigned int Y1_ = h ? pk_[rt_][q_ + 1] : pk_[rt_][q_ + 3]; \
        unsigned int r0_ = (unsigned int)__shfl_xor((int)Y0_, 32); \
        unsigned int r1_ = (unsigned int)__shfl_xor((int)Y1_, 32); \
        Bu[kt_].u[0] = h ? r0_ : pk_[rt_][q_]; \
        Bu[kt_].u[1] = h ? r1_ : pk_[rt_][q_ + 1]; \
        Bu[kt_].u[2] = h ? pk_[rt_][q_ + 2] : r0_; \
        Bu[kt_].u[3] = h ? pk_[rt_][q_ + 3] : r1_; \
    } \
} while (0)

    const float* eB  = srcE + (size_t)b * CPERB;
    const float* mkB = mask + (size_t)b * SLEN;
    const f32x16 z16 = {0.f,0.f,0.f,0.f,0.f,0.f,0.f,0.f,
                        0.f,0.f,0.f,0.f,0.f,0.f,0.f,0.f};

    // E[rt*4+q] = em[T][32rt+8q+4h .. +3]
    f32x4 E[12];
#define LOADE(T) do { \
    const float* pE_ = eB + (size_t)(T) * NTAG + 4 * h; \
    _Pragma("unroll") \
    for (int rt_ = 0; rt_ < 3; ++rt_) { \
        _Pragma("unroll") \
        for (int q_ = 0; q_ < 4; ++q_) \
            E[rt_ * 4 + q_] = *(const f32x4*)(pE_ + 32 * rt_ + 8 * q_); \
    } \
} while (0)

#define STEPCORE(T) do { \
    LOADE(T); \
    f32x16 a0, a1, a2; \
    a0 = __builtin_amdgcn_mfma_f32_32x32x16_bf16(Af[0][0].v, Bu[0].v, z16, 0, 0, 0); \
    a1 = __builtin_amdgcn_mfma_f32_32x32x16_bf16(Af[1][0].v, Bu[0].v, z16, 0, 0, 0); \
    a2 = __builtin_amdgcn_mfma_f32_32x32x16_bf16(Af[2][0].v, Bu[0].v, z16, 0, 0, 0); \
    _Pragma("unroll") \
    for (int kt_ = 1; kt_ < 6; ++kt_) { \
        a0 = __builtin_amdgcn_mfma_f32_32x32x16_bf16(Af[0][kt_].v, Bu[kt_].v, a0, 0, 0, 0); \
        a1 = __builtin_amdgcn_mfma_f32_32x32x16_bf16(Af[1][kt_].v, Bu[kt_].v, a1, 0, 0, 0); \
        a2 = __builtin_amdgcn_mfma_f32_32x32x16_bf16(Af[2][kt_].v, Bu[kt_].v, a2, 0, 0, 0); \
    } \
    float mv_ = mkB[(T)]; \
    if (mv_ != 0.0f) { \
        _Pragma("unroll") \
        for (int r_ = 0; r_ < 16; ++r_) { \
            float e0_ = IEXP ? __expf(E[r_ >> 2][r_ & 3])     : E[r_ >> 2][r_ & 3]; \
            float e1_ = IEXP ? __expf(E[4 + (r_ >> 2)][r_ & 3]) : E[4 + (r_ >> 2)][r_ & 3]; \
            float e2_ = IEXP ? __expf(E[8 + (r_ >> 2)][r_ & 3]) : E[8 + (r_ >> 2)][r_ & 3]; \
            S[0][r_] = a0[r_] * e0_; \
            S[1][r_] = a1[r_] * e1_; \
            S[2][r_] = a2[r_] * e2_; \
        } \
        ls += tmax; \
    } \
} while (0)

#define STEP(T)   do { STEPCORE(T); MAKEB(); } while (0)
#define STEP_R(T) do { STEPCORE(T); RENORM(); MAKEB(); } while (0)

    MAKEB();

    const int nsteps = t1 - t0;        // 256 (255 for last chunk)
    const int nfull  = nsteps >> 3;
    int t = t0;
    #pragma unroll 1
    for (int blk = 0; blk < nfull; ++blk, t += 8) {
        STEP(t + 0); STEP(t + 1); STEP(t + 2); STEP(t + 3);
        STEP(t + 4); STEP(t + 5); STEP(t + 6); STEP_R(t + 7);
    }
    #pragma unroll 1
    while (t < t1) { STEP_R(t); ++t; }

    // store: P[bc][i = 32w2+c][j] fp32 (j = 32rt+8q+4h+{0..3}), Pls per col
    float* Pb = P + ((size_t)bc * NTAG + (32 * w2 + c)) * NTAG + 4 * h;
    #pragma unroll
    for (int rt = 0; rt < 3; ++rt) {
        #pragma unroll
        for (int q = 0; q < 4; ++q) {
            f32x4 v;
            v[0] = S[rt][4 * q + 0]; v[1] = S[rt][4 * q + 1];
            v[2] = S[rt][4 * q + 2]; v[3] = S[rt][4 * q + 3];
            *(f32x4*)(Pb + 32 * rt + 8 * q) = v;
        }
    }
    if (h == 0) Pls[(size_t)bc * NTAG + 32 * w2 + c] = ls;
#undef STEP
#undef STEP_R
#undef STEPCORE
#undef LOADE
#undef MAKEB
#undef RENORM
}

// ---------------------------------------------------------------------------
// Phase 2: per-batch log-domain fold of the NCH chunk operators. (verified)
// ---------------------------------------------------------------------------
__global__ __launch_bounds__(128) void crf_fold(
    const float* __restrict__ em, const float* __restrict__ startT,
    const float* __restrict__ endT,
    const float* __restrict__ P, const float* __restrict__ Pls,
    float* __restrict__ den)
{
    __shared__ float aS[NTAG];
    __shared__ float sRed[2];
    const int b = blockIdx.x, tid = threadIdx.x;
    const bool act = tid < NTAG;

    float A = act ? (startT[tid] + em[(size_t)b * CPERB + tid]) : -1e30f;

    for (int c = 0; c < NCH; ++c) {
        const size_t bc = (size_t)b * NCH + c;
        float v = act ? (A + Pls[bc * NTAG + tid]) : -1e30f;
        float mv = v;
        #pragma unroll
        for (int o = 32; o > 0; o >>= 1) mv = fmaxf(mv, __shfl_xor(mv, o));
        if ((tid & 63) == 0) sRed[tid >> 6] = mv;
        __syncthreads();
        const float m = fmaxf(sRed[0], sRed[1]);
        __syncthreads();
        if (act) aS[tid] = __expf(v - m);
        __syncthreads();
        if (act) {
            const float* Pc = P + bc * (NTAG * NTAG) + tid;
            float dot = 0.f;
            #pragma unroll 8
            for (int i = 0; i < NTAG; ++i)
                dot = fmaf(aS[i], Pc[(size_t)i * NTAG], dot);
            A = m + __logf(dot);
        }
        __syncthreads();
    }

    float Afin = act ? (A + endT[tid]) : -1e30f;
    float mv = Afin;
    #pragma unroll
    for (int o = 32; o > 0; o >>= 1) mv = fmaxf(mv, __shfl_xor(mv, o));
    if ((tid & 63) == 0) sRed[tid >> 6] = mv;
    __syncthreads();
    const float m2 = fmaxf(sRed[0], sRed[1]);
    __syncthreads();
    float ex = act ? __expf(Afin - m2) : 0.f;
    ex = waveSum(ex);
    if ((tid & 63) == 0) sRed[tid >> 6] = ex;
    __syncthreads();
    if (tid == 0) den[b] = m2 + __logf(sRed[0] + sRed[1]);
}

// ---------------------------------------------------------------------------
// Fallback sequential forward (R3-verified structure) — only if ws too small.
// ---------------------------------------------------------------------------
__global__ __launch_bounds__(64, 1) void crf_forward_seq(
    const float* __restrict__ srcE, const float* __restrict__ srcM,
    const float* __restrict__ trans, const float* __restrict__ startT,
    const float* __restrict__ endT, float* __restrict__ den)
{
    __shared__ unsigned int lbuf[2][48 * 20];
    const int tid = threadIdx.x;
    const int g = tid >> 4;
    const int b16 = tid & 15;
    const int b = blockIdx.x * 16 + b16;

    float tm = -1e30f;
    for (int q = tid; q < NTAG * NTAG; q += 64) tm = fmaxf(tm, trans[q]);
    #pragma unroll
    for (int o = 32; o > 0; o >>= 1) tm = fmaxf(tm, __shfl_xor(tm, o));
    const float tmax = tm;

    bf16x8 Af[6][3];
    #pragma unroll
    for (int jt = 0; jt < 6; ++jt) {
        #pragma unroll
        for (int kf = 0; kf < 3; ++kf) {
            U8 u;
            #pragma unroll
            for (int d = 0; d < 4; ++d) {
                int i0 = 32 * kf + 8 * g + 2 * d;
                int j = 16 * jt + b16;
                u.u[d] = pk2bf(__expf(trans[i0 * NTAG + j] - tmax),
                               __expf(trans[(i0 + 1) * NTAG + j] - tmax));
            }
            Af[jt][kf] = u.v;
        }
    }

    float al[24];
    #pragma unroll
    for (int tile = 0; tile < 6; ++tile) {
        #pragma unroll
        for (int r = 0; r < 4; ++r) {
            int j = 16 * tile + 4 * g + r;
            al[tile * 4 + r] = __expf(startT[j]) * __expf(srcE[(size_t)b * CPERB + j]);
        }
    }
    float ls = 0.0f;

#define RENORM2() do { \
    float mx_ = al[0]; \
    _Pragma("unroll") \
    for (int k_ = 1; k_ < 24; ++k_) mx_ = fmaxf(mx_, al[k_]); \
    mx_ = fmaxf(mx_, __shfl_xor(mx_, 16)); \
    mx_ = fmaxf(mx_, __shfl_xor(mx_, 32)); \
    mx_ = fmaxf(mx_, 1e-30f); \
    float inv_ = 1.0f / mx_; \
    ls += __logf(mx_); \
    _Pragma("unroll") \
    for (int k_ = 0; k_ < 24; ++k_) al[k_] *= inv_; \
} while (0)

    U8 Bu[3];
#define MAKEB2(BUF) do { \
    _Pragma("unroll") \
    for (int t_ = 0; t_ < 6; ++t_) { \
        lbuf[BUF][(8 * t_ + 2 * g) * 20 + b16]     = pk2bf(al[4 * t_ + 0], al[4 * t_ + 1]); \
        lbuf[BUF][(8 * t_ + 2 * g + 1) * 20 + b16] = pk2bf(al[4 * t_ + 2], al[4 * t_ + 3]); \
    } \
    __syncthreads(); \
    _Pragma("unroll") \
    for (int kf_ = 0; kf_ < 3; ++kf_) { \
        _Pragma("unroll") \
        for (int d_ = 0; d_ < 4; ++d_) \
            Bu[kf_].u[d_] = lbuf[BUF][(16 * kf_ + 4 * g + d_) * 20 + b16]; \
    } \
} while (0)

    RENORM2();
    MAKEB2(0);
    const f32x4 zf4 = {0.f, 0.f, 0.f, 0.f};

    #pragma unroll 1
    for (int t = 1; t < SLEN; ++t) {
        f32x4 E[6];
        #pragma unroll
        for (int tl = 0; tl < 6; ++tl)
            E[tl] = *(const f32x4*)(srcE + (size_t)b * CPERB + (size_t)t * NTAG + 16 * tl + 4 * g);
        float mv = srcM[(size_t)b * SLEN + t];
        f32x4 acc[6];
        #pragma unroll
        for (int jt = 0; jt < 6; ++jt) {
            f32x4 a_ = __builtin_amdgcn_mfma_f32_16x16x32_bf16(Af[jt][0], Bu[0].v, zf4, 0, 0, 0);
            a_ = __builtin_amdgcn_mfma_f32_16x16x32_bf16(Af[jt][1], Bu[1].v, a_, 0, 0, 0);
            a_ = __builtin_amdgcn_mfma_f32_16x16x32_bf16(Af[jt][2], Bu[2].v, a_, 0, 0, 0);
            acc[jt] = a_;
        }
        bool km = (mv != 0.0f);
        #pragma unroll
        for (int tile = 0; tile < 6; ++tile) {
            #pragma unroll
            for (int r = 0; r < 4; ++r) {
                float nv = acc[tile][r] * __expf(E[tile][r]);
                al[tile * 4 + r] = km ? nv : al[tile * 4 + r];
            }
        }
        ls += km ? tmax : 0.0f;
        if ((t & 3) == 0) RENORM2();
        MAKEB2(t & 1);
        __syncthreads();
    }

    float s = 0.f;
    #pragma unroll
    for (int tile = 0; tile < 6; ++tile) {
        #pragma unroll
        for (int r = 0; r < 4; ++r) {
            int j = 16 * tile + 4 * g + r;
            s += al[tile * 4 + r] * __expf(endT[j]);
        }
    }
    s += __shfl_xor(s, 16);
    s += __shfl_xor(s, 32);
    if (tid < 16) den[b] = ls + __logf(s);
#undef MAKEB2
#undef RENORM2
}

// ---------------------------------------------------------------------------
// Gold-path score (verified, unchanged)
// ---------------------------------------------------------------------------
__global__ __launch_bounds__(256) void crf_score(
    const float* __restrict__ em, const int* __restrict__ tags,
    const float* __restrict__ mask, const float* __restrict__ trans,
    const float* __restrict__ startT, const float* __restrict__ endT,
    float* __restrict__ num)
{
    __shared__ float sS[4], sM[4];
    const int b = blockIdx.x, tid = threadIdx.x;
    const float* emB = em + (size_t)b * CPERB;
    const int* tgB = tags + (size_t)b * SLEN;
    const float* mkB = mask + (size_t)b * SLEN;

    float part = 0.f, mcnt = 0.f;
    for (int t = tid; t < SLEN; t += 256) {
        float mt = mkB[t];
        mcnt += mt;
        if (t >= 1) {
            int tp = tgB[t - 1], tc = tgB[t];
            part += (trans[tp * NTAG + tc] + emB[(size_t)t * NTAG + tc]) * mt;
        }
    }
    part = waveSum(part);
    mcnt = waveSum(mcnt);
    if ((tid & 63) == 0) { sS[tid >> 6] = part; sM[tid >> 6] = mcnt; }
    __syncthreads();
    if (tid == 0) {
        float tot = sS[0] + sS[1] + sS[2] + sS[3];
        int last = (int)(sM[0] + sM[1] + sM[2] + sM[3]) - 1;
        int t0 = tgB[0];
        num[b] = tot + startT[t0] + emB[t0] + endT[tgB[last]];
    }
}

__global__ __launch_bounds__(128) void crf_final(
    const float* __restrict__ den, const float* __restrict__ num,
    float* __restrict__ out)
{
    __shared__ float s2[2];
    const int tid = threadIdx.x;
    float v = den[tid] - num[tid];
    v = waveSum(v);
    if ((tid & 63) == 0) s2[tid >> 6] = v;
    __syncthreads();
    if (tid == 0) out[0] = (s2[0] + s2[1]) * (1.0f / NB);
}

extern "C" void kernel_launch(void* const* d_in, const int* in_sizes, int n_in,
                              void* d_out, int out_size, void* d_ws, size_t ws_size,
                              hipStream_t stream) {
    const float* em     = (const float*)d_in[0];
    const int*   tags   = (const int*)d_in[1];
    const float* mask   = (const float*)d_in[2];
    const float* trans  = (const float*)d_in[3];
    const float* startT = (const float*)d_in[4];
    const float* endT   = (const float*)d_in[5];
    float* out = (float*)d_out;
    float* num = (float*)d_ws;                        // [128]
    float* den = num + NB;                            // [128]

    const size_t szP   = (size_t)NB * NCH * NTAG * NTAG;   // floats
    const size_t szPls = (size_t)NB * NCH * NTAG;
    float* P    = (float*)((char*)d_ws + 4096);
    float* Pls  = P + szP;
    float* eexp = Pls + szPls;
    const size_t need_mid  = 4096 + (szP + szPls) * 4;
    const size_t need_full = need_mid + (size_t)NB * CPERB * 4;

    crf_score<<<NB, 256, 0, stream>>>(em, tags, mask, trans, startT, endT, num);
    if (ws_size >= need_full) {
        exp_pass<<<(NB * CPERB) / (256 * 4), 256, 0, stream>>>(em, eexp);
        crf_chunk32<0><<<3 * NB * NCH, 64, 0, stream>>>(eexp, mask, trans, P, Pls);
        crf_fold<<<NB, 128, 0, stream>>>(em, startT, endT, P, Pls, den);
    } else if (ws_size >= need_mid) {
        crf_chunk32<1><<<3 * NB * NCH, 64, 0, stream>>>(em, mask, trans, P, Pls);
        crf_fold<<<NB, 128, 0, stream>>>(em, startT, endT, P, Pls, den);
    } else {
        crf_forward_seq<<<NB / 16, 64, 0, stream>>>(em, mask, trans, startT, endT, den);
    }
    crf_final<<<1, 128, 0, stream>>>(den, num, out);
}